// Round 1
// baseline (285.067 us; speedup 1.0000x reference)
//
#include <hip/hip_runtime.h>

// Problem constants (from reference): N1=4097, N2=8192
// y = x[1:].reshape(8192, 4096); sum over rows 0..8190, cols 0..4094 of
//   b[i,j] * (y[i,j] - prev^2)^2,  prev = y[i, j-1] (j>0) or y[i, 4095] (j==0)
// out = -a*(x[0]-mu)^2 - sum

#define ROWLEN 4096   // n1-1
#define NCOLS  4095   // n1-2
#define NROWS  8191   // n2-1

__global__ __launch_bounds__(256) void rosen_partial(const float* __restrict__ x,
                                                     const float* __restrict__ b,
                                                     float* __restrict__ partial) {
    const int row = blockIdx.x;
    const float* __restrict__ xr = x + 1 + (size_t)row * ROWLEN;
    const float* __restrict__ br = b + (size_t)row * ROWLEN;

    const float wrap = xr[ROWLEN - 1];   // y[row, 4095] (broadcast load)

    float acc = 0.0f;
    for (int j = threadIdx.x; j < NCOLS; j += 256) {
        float cur  = xr[j];
        float prev = (j == 0) ? wrap : xr[j - 1];
        float d = cur - prev * prev;
        acc += br[j] * d * d;
    }

    // wave-64 shuffle reduction
    #pragma unroll
    for (int off = 32; off > 0; off >>= 1)
        acc += __shfl_down(acc, off, 64);

    __shared__ float s[4];
    const int lane = threadIdx.x & 63;
    const int wid  = threadIdx.x >> 6;
    if (lane == 0) s[wid] = acc;
    __syncthreads();
    if (threadIdx.x == 0)
        partial[row] = s[0] + s[1] + s[2] + s[3];
}

__global__ __launch_bounds__(256) void rosen_final(const float* __restrict__ partial,
                                                   const float* __restrict__ x,
                                                   const float* __restrict__ a,
                                                   const float* __restrict__ mu,
                                                   float* __restrict__ out) {
    float acc = 0.0f;
    for (int i = threadIdx.x; i < NROWS; i += 256)
        acc += partial[i];

    #pragma unroll
    for (int off = 32; off > 0; off >>= 1)
        acc += __shfl_down(acc, off, 64);

    __shared__ float s[4];
    const int lane = threadIdx.x & 63;
    const int wid  = threadIdx.x >> 6;
    if (lane == 0) s[wid] = acc;
    __syncthreads();
    if (threadIdx.x == 0) {
        float total = s[0] + s[1] + s[2] + s[3];
        float d = x[0] - mu[0];
        out[0] = -a[0] * d * d - total;
    }
}

extern "C" void kernel_launch(void* const* d_in, const int* in_sizes, int n_in,
                              void* d_out, int out_size, void* d_ws, size_t ws_size,
                              hipStream_t stream) {
    const float* x  = (const float*)d_in[0];
    const float* a  = (const float*)d_in[1];
    const float* b  = (const float*)d_in[2];
    const float* mu = (const float*)d_in[3];
    float* out = (float*)d_out;
    float* partial = (float*)d_ws;   // NROWS floats = 32 KB scratch

    rosen_partial<<<NROWS, 256, 0, stream>>>(x, b, partial);
    rosen_final<<<1, 256, 0, stream>>>(partial, x, a, mu, out);
}

// Round 2
// 284.164 us; speedup vs baseline: 1.0032x; 1.0032x over previous
//
#include <hip/hip_runtime.h>

// N1=4097, N2=8192. y = x[1:].reshape(8192,4096)
// sum over rows 0..8190, cols j=0..4094 of b[i,j]*(y[i,j]-prev^2)^2,
//   prev = y[i,j-1] (j>0) or y[i,4095] (j==0)
// out = -a*(x[0]-mu)^2 - sum

#define ROWLEN 4096   // n1-1
#define NROWS  8191   // n2-1

// Per row: groups k=0..1023 cover j=4k..4k+3 (group 1023's j=4095 masked out).
// Aligned load p = x[row*4096 + 4k .. 4k+3] = xr[4k-1 .. 4k+2]  (prev values).
// cur values are p shifted left by one; cur.w comes from lane+1's p.x via shfl.
__global__ __launch_bounds__(256) void rosen_partial(const float* __restrict__ x,
                                                     const float* __restrict__ b,
                                                     float* __restrict__ partial) {
    const int row = blockIdx.x;
    const float* __restrict__ xg = x + (size_t)row * ROWLEN;          // xg[t] = x[row*4096+t]; xr[j] = xg[j+1]
    const float4* __restrict__ x4 = (const float4*)xg;                // 16B aligned
    const float4* __restrict__ b4 = (const float4*)(b + (size_t)row * ROWLEN);

    const float wrap = xg[ROWLEN];   // xr[4095] = x[(row+1)*4096], valid for all rows < 8191
    const int lane = threadIdx.x & 63;

    float acc0 = 0.0f, acc1 = 0.0f;
    #pragma unroll
    for (int i = 0; i < 4; ++i) {
        const int k = threadIdx.x + 256 * i;
        float4 p  = x4[k];
        float4 bb = b4[k];

        float nx = __shfl_down(p.x, 1, 64);          // lane l gets lane l+1's p.x = xg[4k+4]
        if (lane == 63) nx = xg[4 * k + 4];          // cross-wave boundary patch (valid: max idx 4096*8191)
        if (k == 0)     p.x = wrap;                  // j=0 wraps to xr[4095]
        if (k == 1023)  bb.w = 0.0f;                 // mask j=4095 (not summed)

        float d0 = p.y - p.x * p.x;                  // j=4k
        float d1 = p.z - p.y * p.y;                  // j=4k+1
        float d2 = p.w - p.z * p.z;                  // j=4k+2
        float d3 = nx  - p.w * p.w;                  // j=4k+3
        acc0 += bb.x * d0 * d0 + bb.z * d2 * d2;
        acc1 += bb.y * d1 * d1 + bb.w * d3 * d3;
    }
    float acc = acc0 + acc1;

    #pragma unroll
    for (int off = 32; off > 0; off >>= 1)
        acc += __shfl_down(acc, off, 64);

    __shared__ float s[4];
    const int wid = threadIdx.x >> 6;
    if (lane == 0) s[wid] = acc;
    __syncthreads();
    if (threadIdx.x == 0)
        partial[row] = s[0] + s[1] + s[2] + s[3];
}

__global__ __launch_bounds__(256) void rosen_final(const float* __restrict__ partial,
                                                   const float* __restrict__ x,
                                                   const float* __restrict__ a,
                                                   const float* __restrict__ mu,
                                                   float* __restrict__ out) {
    float acc = 0.0f;
    for (int i = threadIdx.x; i < NROWS; i += 256)
        acc += partial[i];

    #pragma unroll
    for (int off = 32; off > 0; off >>= 1)
        acc += __shfl_down(acc, off, 64);

    __shared__ float s[4];
    const int lane = threadIdx.x & 63;
    const int wid  = threadIdx.x >> 6;
    if (lane == 0) s[wid] = acc;
    __syncthreads();
    if (threadIdx.x == 0) {
        float total = s[0] + s[1] + s[2] + s[3];
        float d = x[0] - mu[0];
        out[0] = -a[0] * d * d - total;
    }
}

extern "C" void kernel_launch(void* const* d_in, const int* in_sizes, int n_in,
                              void* d_out, int out_size, void* d_ws, size_t ws_size,
                              hipStream_t stream) {
    const float* x  = (const float*)d_in[0];
    const float* a  = (const float*)d_in[1];
    const float* b  = (const float*)d_in[2];
    const float* mu = (const float*)d_in[3];
    float* out = (float*)d_out;
    float* partial = (float*)d_ws;   // NROWS floats = 32 KB scratch

    rosen_partial<<<NROWS, 256, 0, stream>>>(x, b, partial);
    rosen_final<<<1, 256, 0, stream>>>(partial, x, a, mu, out);
}

// Round 3
// 282.575 us; speedup vs baseline: 1.0088x; 1.0056x over previous
//
#include <hip/hip_runtime.h>

// N1=4097, N2=8192. y = x[1:].reshape(8192,4096)
// sum over rows 0..8190, cols j=0..4094 of b[i,j]*(y[i,j]-prev^2)^2,
//   prev = y[i,j-1] (j>0) or y[i,4095] (j==0)
// out = -a*(x[0]-mu)^2 - sum

#define ROWLEN 4096   // n1-1
#define NROWS  8191   // n2-1

// Per row: groups k=0..1023 cover j=4k..4k+3 (group 1023's j=4095 masked out).
// Aligned load p = x4[k] = xg[4k..4k+3] (the PREV values for j=4k..4k+3).
// cur values are p shifted left by one; cur.w comes from lane+1's p.x via shfl
// (lane 63 patches from a hoisted scalar load).
// All global loads are issued BEFORE any use -> 8+ outstanding per wave (MLP).
__global__ __launch_bounds__(256) void rosen_partial(const float* __restrict__ x,
                                                     const float* __restrict__ b,
                                                     float* __restrict__ partial) {
    const int row = blockIdx.x;
    const float* __restrict__ xg = x + (size_t)row * ROWLEN;   // xr[j] = xg[j+1]
    const float4* __restrict__ x4 = (const float4*)xg;
    const float4* __restrict__ b4 = (const float4*)(b + (size_t)row * ROWLEN);
    const int lane = threadIdx.x & 63;

    // ---- issue phase: everything in flight before first use ----
    float4 px[4], pb[4];
    #pragma unroll
    for (int i = 0; i < 4; ++i) px[i] = x4[threadIdx.x + 256 * i];
    #pragma unroll
    for (int i = 0; i < 4; ++i) pb[i] = b4[threadIdx.x + 256 * i];

    float patch[4] = {0.f, 0.f, 0.f, 0.f};
    if (lane == 63) {
        #pragma unroll
        for (int i = 0; i < 4; ++i)
            patch[i] = xg[4 * (threadIdx.x + 256 * i) + 4];   // max idx 4096 -> last x elem, valid
    }
    float wrap = 0.f;
    if (threadIdx.x == 0) wrap = xg[ROWLEN];   // xr[4095], only thread 0 (k==0) needs it

    // ---- compute phase ----
    float acc0 = 0.0f, acc1 = 0.0f;
    #pragma unroll
    for (int i = 0; i < 4; ++i) {
        const int k = threadIdx.x + 256 * i;
        float4 p  = px[i];
        float4 bb = pb[i];

        float nx = __shfl_down(p.x, 1, 64);   // lane l <- lane l+1's p.x = xg[4k+4]
        if (lane == 63) nx = patch[i];
        if (k == 0)     p.x = wrap;           // j=0 wraps to xr[4095]
        if (k == 1023)  bb.w = 0.0f;          // j=4095 not summed

        float d0 = p.y - p.x * p.x;
        float d1 = p.z - p.y * p.y;
        float d2 = p.w - p.z * p.z;
        float d3 = nx  - p.w * p.w;
        acc0 += bb.x * d0 * d0 + bb.z * d2 * d2;
        acc1 += bb.y * d1 * d1 + bb.w * d3 * d3;
    }
    float acc = acc0 + acc1;

    #pragma unroll
    for (int off = 32; off > 0; off >>= 1)
        acc += __shfl_down(acc, off, 64);

    __shared__ float s[4];
    const int wid = threadIdx.x >> 6;
    if (lane == 0) s[wid] = acc;
    __syncthreads();
    if (threadIdx.x == 0)
        partial[row] = s[0] + s[1] + s[2] + s[3];
}

__global__ __launch_bounds__(256) void rosen_final(const float* __restrict__ partial,
                                                   const float* __restrict__ x,
                                                   const float* __restrict__ a,
                                                   const float* __restrict__ mu,
                                                   float* __restrict__ out) {
    float acc = 0.0f;
    for (int i = threadIdx.x; i < NROWS; i += 256)
        acc += partial[i];

    #pragma unroll
    for (int off = 32; off > 0; off >>= 1)
        acc += __shfl_down(acc, off, 64);

    __shared__ float s[4];
    const int lane = threadIdx.x & 63;
    const int wid  = threadIdx.x >> 6;
    if (lane == 0) s[wid] = acc;
    __syncthreads();
    if (threadIdx.x == 0) {
        float total = s[0] + s[1] + s[2] + s[3];
        float d = x[0] - mu[0];
        out[0] = -a[0] * d * d - total;
    }
}

extern "C" void kernel_launch(void* const* d_in, const int* in_sizes, int n_in,
                              void* d_out, int out_size, void* d_ws, size_t ws_size,
                              hipStream_t stream) {
    const float* x  = (const float*)d_in[0];
    const float* a  = (const float*)d_in[1];
    const float* b  = (const float*)d_in[2];
    const float* mu = (const float*)d_in[3];
    float* out = (float*)d_out;
    float* partial = (float*)d_ws;   // NROWS floats = 32 KB scratch

    rosen_partial<<<NROWS, 256, 0, stream>>>(x, b, partial);
    rosen_final<<<1, 256, 0, stream>>>(partial, x, a, mu, out);
}

// Round 5
// 278.618 us; speedup vs baseline: 1.0231x; 1.0142x over previous
//
#include <hip/hip_runtime.h>

// N1=4097, N2=8192. y = x[1:].reshape(8192,4096)
// Flat form: for t in [0, 8191*4096), col = t & 4095:
//   col != 4095: term(t) = b[t] * (x[t+1] - prev^2)^2
//     prev = x[t]        (col != 0)
//     prev = x[t+4096]   (col == 0, wrap to y[row,4095])
//   col == 4095: excluded
// out = -a*(x[0]-mu)^2 - sum(term)

#define TOTAL   (8191u * 4096u)       // 33,550,336 elements
#define GROUPS  (TOTAL / 8u)          // 4,193,792 = 512 * 8191 groups of 8
#define GRID    2048
#define BLOCK   256
#define NTHREAD (GRID * BLOCK)                        // 524,288
#define NPASS   ((GROUPS + NTHREAD - 1) / NTHREAD)    // 8 (ceil; last pass partial)

__global__ __launch_bounds__(BLOCK) void rosen_partial(const float* __restrict__ x,
                                                       const float* __restrict__ b,
                                                       float* __restrict__ partial) {
    const unsigned tid = blockIdx.x * BLOCK + threadIdx.x;
    const float4* __restrict__ x4 = (const float4*)x;
    const float4* __restrict__ b4 = (const float4*)b;

    // ---- prologue: load pass 0 (tid < NTHREAD <= GROUPS, always valid) ----
    unsigned g = tid;
    bool cvalid = true;
    size_t e = (size_t)g * 8;
    float4 cp0 = x4[e >> 2], cp1 = x4[(e >> 2) + 1];
    float  cs  = x[e + 8];
    float4 cb0 = b4[e >> 2], cb1 = b4[(e >> 2) + 1];
    float  cw  = 0.0f;
    if ((g & 511u) == 0u) cw = x[e + 4096];      // wrap value for col==0 group

    float acc = 0.0f;

    #pragma unroll 1
    for (int pass = 0; pass < NPASS; ++pass) {
        // ---- prefetch next pass (address clamped when out of range) ----
        unsigned gn = g + NTHREAD;
        bool nvalid = (gn < GROUPS);
        unsigned gl = nvalid ? gn : g;           // clamp: harmless L1-hit re-load
        size_t en = (size_t)gl * 8;
        float4 np0 = x4[en >> 2], np1 = x4[(en >> 2) + 1];
        float  ns  = x[en + 8];
        float4 nb0 = b4[en >> 2], nb1 = b4[(en >> 2) + 1];
        float  nw  = 0.0f;
        if ((gl & 511u) == 0u) nw = x[en + 4096];

        // ---- compute current pass ----
        if (cvalid) {
            float px = cp0.x;
            if ((g & 511u) == 0u)   px = cw;     // col 0: prev wraps
            if ((g & 511u) == 511u) cb1.w = 0.0f;// col 4095: masked

            float d0 = cp0.y - px    * px;
            float d1 = cp0.z - cp0.y * cp0.y;
            float d2 = cp0.w - cp0.z * cp0.z;
            float d3 = cp1.x - cp0.w * cp0.w;
            float d4 = cp1.y - cp1.x * cp1.x;
            float d5 = cp1.z - cp1.y * cp1.y;
            float d6 = cp1.w - cp1.z * cp1.z;
            float d7 = cs    - cp1.w * cp1.w;
            acc += cb0.x * d0 * d0 + cb0.y * d1 * d1
                 + cb0.z * d2 * d2 + cb0.w * d3 * d3
                 + cb1.x * d4 * d4 + cb1.y * d5 * d5
                 + cb1.z * d6 * d6 + cb1.w * d7 * d7;
        }

        // ---- rotate buffers ----
        g = gn; cvalid = nvalid;
        cp0 = np0; cp1 = np1; cs = ns; cb0 = nb0; cb1 = nb1; cw = nw;
    }

    // wave-64 reduction
    #pragma unroll
    for (int off = 32; off > 0; off >>= 1)
        acc += __shfl_down(acc, off, 64);

    __shared__ float s[4];
    const int lane = threadIdx.x & 63;
    const int wid  = threadIdx.x >> 6;
    if (lane == 0) s[wid] = acc;
    __syncthreads();
    if (threadIdx.x == 0)
        partial[blockIdx.x] = s[0] + s[1] + s[2] + s[3];
}

__global__ __launch_bounds__(256) void rosen_final(const float* __restrict__ partial,
                                                   const float* __restrict__ x,
                                                   const float* __restrict__ a,
                                                   const float* __restrict__ mu,
                                                   float* __restrict__ out) {
    float acc = 0.0f;
    for (int i = threadIdx.x; i < GRID; i += 256)
        acc += partial[i];

    #pragma unroll
    for (int off = 32; off > 0; off >>= 1)
        acc += __shfl_down(acc, off, 64);

    __shared__ float s[4];
    const int lane = threadIdx.x & 63;
    const int wid  = threadIdx.x >> 6;
    if (lane == 0) s[wid] = acc;
    __syncthreads();
    if (threadIdx.x == 0) {
        float total = s[0] + s[1] + s[2] + s[3];
        float d = x[0] - mu[0];
        out[0] = -a[0] * d * d - total;
    }
}

extern "C" void kernel_launch(void* const* d_in, const int* in_sizes, int n_in,
                              void* d_out, int out_size, void* d_ws, size_t ws_size,
                              hipStream_t stream) {
    const float* x  = (const float*)d_in[0];
    const float* a  = (const float*)d_in[1];
    const float* b  = (const float*)d_in[2];
    const float* mu = (const float*)d_in[3];
    float* out = (float*)d_out;
    float* partial = (float*)d_ws;   // GRID floats = 8 KB scratch

    rosen_partial<<<GRID, BLOCK, 0, stream>>>(x, b, partial);
    rosen_final<<<1, 256, 0, stream>>>(partial, x, a, mu, out);
}